// Round 1
// baseline (164.331 us; speedup 1.0000x reference)
//
#include <hip/hip_runtime.h>

// PooledMSELoss: mean((box9(pred) - box9(target))^2)
//   = mean(box9(pred - target)^2)   [box filter is linear]
// B,C,T,H,W = 4,2,8,512,512 fp32; POOL=9, zero padding on H,W, /81 scaling.

constexpr int Hh   = 512;
constexpr int Ww   = 512;
constexpr int PAD  = 4;      // POOL/2
constexpr int ROWS = 64;     // output rows per block
constexpr int CHUNK = 8;     // rows per barrier chunk
constexpr int NBLK_PER_IMG = Hh / ROWS;   // 8
constexpr int LROW = Ww + 2 * PAD;        // 520 floats per LDS row

__global__ __launch_bounds__(256, 2)
void pooled_mse_kernel(const float* __restrict__ pred,
                       const float* __restrict__ tgt,
                       float* __restrict__ out) {
    __shared__ float lds[CHUNK][LROW];

    const int tid = threadIdx.x;
    const int img = blockIdx.x / NBLK_PER_IMG;          // 0..63
    const int y0  = (blockIdx.x % NBLK_PER_IMG) * ROWS; // 0,64,...,448

    const size_t ibase = (size_t)img * Hh * Ww;
    const float2* p2 = (const float2*)(pred + ibase);
    const float2* t2 = (const float2*)(tgt + ibase);
    const int c2 = tid;   // this thread owns columns 2*tid, 2*tid+1

    // Zero the horizontal halos once (never overwritten afterwards).
    if (tid < CHUNK) {
        #pragma unroll
        for (int k = 0; k < PAD; ++k) {
            lds[tid][k] = 0.0f;
            lds[tid][PAD + Ww + k] = 0.0f;
        }
    }

    auto loadrow = [&](int y) -> float2 {
        if ((unsigned)y < (unsigned)Hh) {
            float2 a = p2[(size_t)y * (Ww / 2) + c2];
            float2 b = t2[(size_t)y * (Ww / 2) + c2];
            return make_float2(a.x - b.x, a.y - b.y);
        }
        return make_float2(0.0f, 0.0f);   // zero padding rows
    };

    // Ring of the previous 8 rows of d; cs = their column sum.
    float2 ring[8];
    float2 cs = make_float2(0.0f, 0.0f);
    #pragma unroll
    for (int i = 0; i < 8; ++i) {
        ring[i] = loadrow(y0 - PAD + i);
        cs.x += ring[i].x;
        cs.y += ring[i].y;
    }
    __syncthreads();   // halo zeros visible

    float acc = 0.0f;

    for (int ch = 0; ch < ROWS / CHUNK; ++ch) {
        // ---- Phase A: vertical running 9-sums for CHUNK rows -> LDS ----
        #pragma unroll
        for (int r = 0; r < CHUNK; ++r) {
            const int y = y0 + ch * CHUNK + r;
            float2 nd = loadrow(y + PAD);                 // incoming row y+4
            float s9x = cs.x + nd.x;                      // rows y-4..y+4
            float s9y = cs.y + nd.y;
            lds[r][PAD + 2 * tid]     = s9x;
            lds[r][PAD + 2 * tid + 1] = s9y;
            cs.x = s9x - ring[0].x;                       // drop row y-4
            cs.y = s9y - ring[0].y;
            #pragma unroll
            for (int i = 0; i < 7; ++i) ring[i] = ring[i + 1];
            ring[7] = nd;
        }
        __syncthreads();

        // ---- Phase B: horizontal 9-sums + accumulate squares ----
        #pragma unroll
        for (int r = 0; r < CHUNK; ++r) {
            float s[10];
            #pragma unroll
            for (int k = 0; k < 10; ++k) s[k] = lds[r][2 * tid + k];
            float t8 = s[1];
            #pragma unroll
            for (int k = 2; k <= 8; ++k) t8 += s[k];
            float o0 = t8 + s[0];   // 9-sum for column 2*tid
            float o1 = t8 + s[9];   // 9-sum for column 2*tid+1
            acc = fmaf(o0, o0, acc);
            acc = fmaf(o1, o1, acc);
        }
        __syncthreads();   // before next chunk overwrites LDS
    }

    // ---- Reduction: wave shuffle, then cross-wave via LDS, one atomic ----
    #pragma unroll
    for (int off = 32; off > 0; off >>= 1)
        acc += __shfl_down(acc, off, 64);

    __shared__ float wsum[4];
    const int wid = tid >> 6, lane = tid & 63;
    if (lane == 0) wsum[wid] = acc;
    __syncthreads();
    if (tid == 0) {
        float b = wsum[0] + wsum[1] + wsum[2] + wsum[3];
        // raw sums are 81x the smoothed values; mean over B*C*T*H*W
        const float scale = 1.0f / (81.0f * 81.0f * 16777216.0f);
        atomicAdd(out, b * scale);
    }
}

extern "C" void kernel_launch(void* const* d_in, const int* in_sizes, int n_in,
                              void* d_out, int out_size, void* d_ws, size_t ws_size,
                              hipStream_t stream) {
    const float* pred = (const float*)d_in[0];
    const float* tgt  = (const float*)d_in[1];
    float* out = (float*)d_out;

    // d_out is re-poisoned to 0xAA before every timed launch.
    hipMemsetAsync(out, 0, sizeof(float), stream);

    const int nblocks = 64 * NBLK_PER_IMG;   // 64 images * 8 row-blocks = 512
    pooled_mse_kernel<<<nblocks, 256, 0, stream>>>(pred, tgt, out);
}